// Round 1
// baseline (1803.890 us; speedup 1.0000x reference)
//
#include <hip/hip_runtime.h>

// 2-layer tanh RNN (B=4096, T=512, D=30) + MLP head (30->15->15->1), fp32.
// Layout: 32 lanes per batch chain (lane j owns state element j), 2 chains/wave,
// 8 chains per 256-thread block -> 512 blocks = 8 waves/CU. All cross-lane
// broadcast via per-group LDS rows + wave-internal ordering (no __syncthreads).
// Recurrent weight rows live in VGPRs; h broadcasts read back as ds_read_b128.

namespace {
constexpr int T = 512;
constexpr int D = 30;   // hidden size
constexpr int H = 15;   // head hidden size
constexpr int GPB = 8;  // chains (groups of 32 lanes) per block
constexpr int BLOCK = 32 * GPB;

typedef float f2 __attribute__((ext_vector_type(2), aligned(8)));
typedef float f4 __attribute__((ext_vector_type(4), aligned(16)));

// tanh(x) = 1 - 2/(exp(2x)+1): NaN-free at +/-inf, ~1e-6 abs err.
__device__ __forceinline__ float fast_tanh(float x) {
  float e = __expf(2.0f * x);                       // v_mul + v_exp_f32
  return 1.0f - 2.0f * __builtin_amdgcn_rcpf(e + 1.0f);
}
}  // namespace

__global__ __launch_bounds__(BLOCK, 2) void rnn_head_fused(
    const float* __restrict__ x,
    const float* __restrict__ Wih1, const float* __restrict__ Whh1,
    const float* __restrict__ bih1, const float* __restrict__ bhh1,
    const float* __restrict__ Wih2, const float* __restrict__ Whh2,
    const float* __restrict__ bih2, const float* __restrict__ bhh2,
    const float* __restrict__ W1, const float* __restrict__ b1,
    const float* __restrict__ W2, const float* __restrict__ b2,
    const float* __restrict__ W3, const float* __restrict__ b3,
    float* __restrict__ out) {
  const int tid = threadIdx.x;
  const int g = tid >> 5;        // group (chain) within block
  const int j = tid & 31;        // lane within group = state element index
  const long e = (long)blockIdx.x * GPB + g;  // batch chain id

  __shared__ float h1b[GPB][32];  // h1 broadcast rows (128B stride, bank-clean)
  __shared__ float h2b[GPB][32];
  __shared__ float v1b[GPB][16];

  const int jr = (j < D) ? j : (D - 1);  // clamped row index (lanes 30,31)
  const int jh = (j < H) ? j : (H - 1);

  // ---- per-lane weight rows in registers ----
  float wih1[D], whh1[D], wih2[D], whh2[D], w1r[D];
#pragma unroll
  for (int k = 0; k < D; ++k) {
    wih1[k] = Wih1[jr * D + k];
    whh1[k] = Whh1[jr * D + k];
    wih2[k] = Wih2[jr * D + k];
    whh2[k] = Whh2[jr * D + k];
    w1r[k] = W1[jh * D + k];
  }
  float w2r[16];
#pragma unroll
  for (int k = 0; k < H; ++k) w2r[k] = W2[jh * H + k];
  w2r[15] = 0.0f;  // kills the pad slot of v1b

  const float bias1 = bih1[jr] + bhh1[jr];   // xw1 bias (bih1+bhh1)
  const float bias2 = bih2[jr] + bhh2[jr];
  const float b1r = b1[jh];
  const float b2r = b2[jh];
  const float w3r = (j < H) ? W3[j] : 0.0f;
  const float b3r = b3[0];

  const float* xr = x + e * (long)T * D;
  float* outr = out + e * (long)T;

  const f4* h1p = (const f4*)(&h1b[g][0]);
  const f4* h2p = (const f4*)(&h2b[g][0]);
  const f4* v1p = (const f4*)(&v1b[g][0]);

  // rec1/rec2 hold Whh * h_{t-1} (computed at the end of the previous step).
  float rec1 = 0.0f, rec2 = 0.0f;

  // prefetch x_0 (15 x float2 broadcast loads; 120*t is always 8B aligned)
  f2 xv[15];
#pragma unroll
  for (int k = 0; k < 15; ++k) xv[k] = ((const f2*)xr)[k];

  for (int t = 0; t < T; ++t) {
    // ---- layer-1 input projection: Wih1[j,:] . x_t ----
    float a0 = 0.0f, a1 = 0.0f;
#pragma unroll
    for (int k = 0; k < 15; ++k) {
      a0 = fmaf(wih1[2 * k], xv[k].x, a0);
      a1 = fmaf(wih1[2 * k + 1], xv[k].y, a1);
    }
    // prefetch x_{t+1} (independent; in flight during the rest of the step)
    {
      const int tn = (t + 1 < T) ? (t + 1) : t;
      const f2* xn = (const f2*)(xr + (long)tn * D);
#pragma unroll
      for (int k = 0; k < 15; ++k) xv[k] = xn[k];
    }

    float h1 = fast_tanh(a0 + a1 + bias1 + rec1);

    // ---- broadcast h1 within the group ----
    __builtin_amdgcn_wave_barrier();
    h1b[g][j] = (j < D) ? h1 : 0.0f;
    __builtin_amdgcn_wave_barrier();
    f4 g1[8];
#pragma unroll
    for (int q = 0; q < 8; ++q) g1[q] = h1p[q];
    __builtin_amdgcn_wave_barrier();

    // next step's rec1 = Whh1[j,:].h1  +  layer-2 input proj = Wih2[j,:].h1
    float r1a = 0.0f, r1b = 0.0f, p2a = 0.0f, p2b = 0.0f;
#pragma unroll
    for (int k = 0; k < D; ++k) {
      const float hk = g1[k >> 2][k & 3];
      if (k & 1) {
        r1b = fmaf(whh1[k], hk, r1b);
        p2b = fmaf(wih2[k], hk, p2b);
      } else {
        r1a = fmaf(whh1[k], hk, r1a);
        p2a = fmaf(wih2[k], hk, p2a);
      }
    }
    rec1 = r1a + r1b;

    float h2 = fast_tanh(p2a + p2b + bias2 + rec2);

    // ---- broadcast h2 ----
    __builtin_amdgcn_wave_barrier();
    h2b[g][j] = (j < D) ? h2 : 0.0f;
    __builtin_amdgcn_wave_barrier();
    f4 g2[8];
#pragma unroll
    for (int q = 0; q < 8; ++q) g2[q] = h2p[q];
    __builtin_amdgcn_wave_barrier();

    // next step's rec2 = Whh2[j,:].h2  +  head layer 1: W1[j,:].h2
    float r2a = 0.0f, r2b = 0.0f, u1a = 0.0f, u1b = 0.0f;
#pragma unroll
    for (int k = 0; k < D; ++k) {
      const float hk = g2[k >> 2][k & 3];
      if (k & 1) {
        r2b = fmaf(whh2[k], hk, r2b);
        u1b = fmaf(w1r[k], hk, u1b);
      } else {
        r2a = fmaf(whh2[k], hk, r2a);
        u1a = fmaf(w1r[k], hk, u1a);
      }
    }
    rec2 = r2a + r2b;

    float v1 = fast_tanh(u1a + u1b + b1r);

    // ---- broadcast v1 (15 wide, slot 15 zeroed) ----
    __builtin_amdgcn_wave_barrier();
    if (j < H)
      v1b[g][j] = v1;
    else if (j == H)
      v1b[g][H] = 0.0f;
    __builtin_amdgcn_wave_barrier();
    f4 gv[4];
#pragma unroll
    for (int q = 0; q < 4; ++q) gv[q] = v1p[q];
    __builtin_amdgcn_wave_barrier();

    // head layer 2: W2[j,:].v1
    float u2a = 0.0f, u2b = 0.0f;
#pragma unroll
    for (int k = 0; k < 16; ++k) {
      const float vk = gv[k >> 2][k & 3];
      if (k & 1)
        u2b = fmaf(w2r[k], vk, u2b);
      else
        u2a = fmaf(w2r[k], vk, u2a);
    }
    float v2 = fast_tanh(u2a + u2b + b2r);

    // head layer 3: reduce W3 . v2 over lanes 0..14 (within 16-lane rows)
    float p = w3r * v2;  // 0 for lanes >= 15
    p += __shfl_down(p, 8, 16);
    p += __shfl_down(p, 4, 16);
    p += __shfl_down(p, 2, 16);
    p += __shfl_down(p, 1, 16);
    if (j == 0) outr[t] = p + b3r;
  }
}

extern "C" void kernel_launch(void* const* d_in, const int* in_sizes, int n_in,
                              void* d_out, int out_size, void* d_ws,
                              size_t ws_size, hipStream_t stream) {
  const float* x = (const float*)d_in[0];
  const float* Wih1 = (const float*)d_in[1];
  const float* Whh1 = (const float*)d_in[2];
  const float* bih1 = (const float*)d_in[3];
  const float* bhh1 = (const float*)d_in[4];
  const float* Wih2 = (const float*)d_in[5];
  const float* Whh2 = (const float*)d_in[6];
  const float* bih2 = (const float*)d_in[7];
  const float* bhh2 = (const float*)d_in[8];
  const float* W1 = (const float*)d_in[9];
  const float* b1 = (const float*)d_in[10];
  const float* W2 = (const float*)d_in[11];
  const float* b2 = (const float*)d_in[12];
  const float* W3 = (const float*)d_in[13];
  const float* b3 = (const float*)d_in[14];

  const int B = in_sizes[0] / (T * D);  // 4096
  dim3 grid(B / GPB), block(BLOCK);
  hipLaunchKernelGGL(rnn_head_fused, grid, block, 0, stream, x, Wih1, Whh1,
                     bih1, bhh1, Wih2, Whh2, bih2, bhh2, W1, b1, W2, b2, W3, b3,
                     (float*)d_out);
}

// Round 2
// 1281.738 us; speedup vs baseline: 1.4074x; 1.4074x over previous
//
#include <hip/hip_runtime.h>

// 2-layer tanh RNN (B=4096, T=512, D=30) + MLP head (30->15->15->1), fp32.
//
// Layout: ONE wave (64 lanes) per batch chain, block=64 -> 4096 blocks
// (16 waves/CU, 4/SIMD). The two 32-lane halves hold DIFFERENT weight arrays
// so each broadcast-dot phase computes two matvecs in one instruction stream:
//   phase1: lower = Whh1 rows (rec1_next), upper = Wih2 rows (layer2 in-proj)
//   phase2: lower = [W1 rows; W2 rows]   , upper = Whh2 rows (rec2_next)
// Hidden-state broadcast via v_readlane -> SGPR (wave-uniform), consumed as
// the scalar operand of v_fma. No LDS; no spills (~110 VGPRs).
// x addresses depend only on blockIdx (block = 1 wave) -> compiler emits
// s_load into SGPRs; prefetched one step ahead.

namespace {
constexpr int T = 512;
constexpr int D = 30;   // hidden size
constexpr int H = 15;   // head hidden size

// tanh(x) = 1 - 2/(exp(2x)+1): NaN-free at +/-inf, ~1e-6 abs err.
__device__ __forceinline__ float fast_tanh(float x) {
  float e = __expf(2.0f * x);
  return 1.0f - 2.0f * __builtin_amdgcn_rcpf(e + 1.0f);
}

// Broadcast lane `lane`'s value to all lanes via v_readlane (SGPR result).
__device__ __forceinline__ float bcast(float v, int lane) {
  return __int_as_float(__builtin_amdgcn_readlane(__float_as_int(v), lane));
}
}  // namespace

__global__ __launch_bounds__(64, 4) void rnn_head_fused(
    const float* __restrict__ x,
    const float* __restrict__ Wih1, const float* __restrict__ Whh1,
    const float* __restrict__ bih1, const float* __restrict__ bhh1,
    const float* __restrict__ Wih2, const float* __restrict__ Whh2,
    const float* __restrict__ bih2, const float* __restrict__ bhh2,
    const float* __restrict__ W1, const float* __restrict__ b1,
    const float* __restrict__ W2, const float* __restrict__ b2,
    const float* __restrict__ W3, const float* __restrict__ b3,
    float* __restrict__ out) {
  const int j = threadIdx.x;           // 0..63
  const bool lo = (j < 32);            // lower half?
  const int ju = lo ? j : (j - 32);    // index within half
  const int r = (ju < D) ? ju : (D - 1);  // clamped row index 0..29

  // ---- per-lane weight rows (registers) ----
  // dk : Wih1 row r on BOTH halves (xa computed redundantly; h1 read from lower)
  // aw : lower = Whh1 row r, upper = Wih2 row r
  // bw : lower j<15 = W1 row j; lower 15<=j<30 = W2 row (j-15) (cols 0..14);
  //      upper = Whh2 row r
  float dk[D], aw[D], bw[D];
  const float* Drow = Wih1 + r * D;
  const float* Arow = (lo ? Whh1 : Wih2) + r * D;
#pragma unroll
  for (int k = 0; k < D; ++k) {
    dk[k] = Drow[k];
    aw[k] = Arow[k];
  }
#pragma unroll
  for (int k = 0; k < D; ++k) {
    float v;
    if (!lo)
      v = Whh2[r * D + k];
    else if (j < H)
      v = W1[j * D + k];
    else if (j < D && k < H)
      v = W2[(j - H) * H + k];
    else
      v = 0.0f;
    bw[k] = v;
  }

  // biasA: lower = bih1+bhh1 (for h1), upper = bih2+bhh2 (for h2)
  const float biasA = lo ? (bih1[r] + bhh1[r]) : (bih2[r] + bhh2[r]);
  // biasB: lanes 0..14 = b1 (for v1), lanes 15..29 = b2 (for v2), else 0
  const float biasB = (j < H) ? b1[j] : ((j < D) ? b2[j - H] : 0.0f);
  const bool mid = (j >= H) && (j < D);        // lanes 15..29 hold v2
  const float w3v = mid ? W3[j - H] : 0.0f;
  const float sb3 = b3[0];

  const float* xr = x + (long)blockIdx.x * (T * D);
  float* outp = out + (long)blockIdx.x * T;

  // preload x_0 (uniform address -> s_load)
  float sx[D];
#pragma unroll
  for (int k = 0; k < D; ++k) sx[k] = xr[k];

  float rec1 = 0.0f, rec2 = 0.0f;  // Whh1*h1_{t-1} (lower) / Whh2*h2_{t-1} (upper)

  for (int t = 0; t < T; ++t) {
    // ---- layer-1 input projection: Wih1[r,:] . x_t (sgpr operands) ----
    float xa = 0.0f, xb = 0.0f;
#pragma unroll
    for (int k = 0; k < D; ++k) {
      if (k & 1)
        xb = fmaf(dk[k], sx[k], xb);
      else
        xa = fmaf(dk[k], sx[k], xa);
    }
    const float h1 = fast_tanh(xa + xb + biasA + rec1);  // valid on lanes 0..29

    // prefetch x_{t+1} (uniform s_loads; full step of latency slack)
    {
      const float* xn = xr + ((t + 1 < T) ? (t + 1) : t) * D;
#pragma unroll
      for (int k = 0; k < D; ++k) sx[k] = xn[k];
    }

    // ---- phase 1: broadcast h1 (lanes 0..29); lower->rec1_next, upper->p2 ----
    float p1a = 0.0f, p1b = 0.0f;
#pragma unroll
    for (int k = 0; k < D; ++k) {
      const float s = bcast(h1, k);
      if (k & 1)
        p1b = fmaf(aw[k], s, p1b);
      else
        p1a = fmaf(aw[k], s, p1a);
    }
    const float p1 = p1a + p1b;
    rec1 = p1;                                           // meaningful on lower
    const float h2 = fast_tanh(p1 + biasA + rec2);       // valid on lanes 32..61

    // ---- phase 2: broadcast h2 (lanes 32..61); lower->u1, upper->rec2_next ----
    float p2a = 0.0f, p2b = 0.0f;
#pragma unroll
    for (int k = 0; k < D; ++k) {
      const float s = bcast(h2, 32 + k);
      if (k & 1)
        p2b = fmaf(bw[k], s, p2b);
      else
        p2a = fmaf(bw[k], s, p2a);
    }
    const float p2 = p2a + p2b;
    rec2 = p2;                                           // meaningful on upper
    const float v1 = fast_tanh(p2 + biasB);              // valid on lanes 0..14

    // ---- phase 3: broadcast v1 (lanes 0..14); lanes 15..29 -> u2 ----
    float p3a = 0.0f, p3b = 0.0f;
#pragma unroll
    for (int k = 0; k < H; ++k) {
      const float s = bcast(v1, k);
      if (k & 1)
        p3b = fmaf(bw[k], s, p3b);
      else
        p3a = fmaf(bw[k], s, p3a);
    }
    const float v2 = fast_tanh(p3a + p3b + biasB);       // valid on lanes 15..29

    // ---- head layer 3: y = sum_i W3[i] * v2[15+i] + b3 ----
    float p = mid ? (w3v * v2) : 0.0f;  // cndmask kills NaN from garbage lanes
    p += __shfl_xor(p, 16, 32);
    p += __shfl_xor(p, 8, 32);
    p += __shfl_xor(p, 4, 32);
    p += __shfl_xor(p, 2, 32);
    p += __shfl_xor(p, 1, 32);
    if (j == 0) outp[t] = p + sb3;
  }
}

extern "C" void kernel_launch(void* const* d_in, const int* in_sizes, int n_in,
                              void* d_out, int out_size, void* d_ws,
                              size_t ws_size, hipStream_t stream) {
  const float* x = (const float*)d_in[0];
  const float* Wih1 = (const float*)d_in[1];
  const float* Whh1 = (const float*)d_in[2];
  const float* bih1 = (const float*)d_in[3];
  const float* bhh1 = (const float*)d_in[4];
  const float* Wih2 = (const float*)d_in[5];
  const float* Whh2 = (const float*)d_in[6];
  const float* bih2 = (const float*)d_in[7];
  const float* bhh2 = (const float*)d_in[8];
  const float* W1 = (const float*)d_in[9];
  const float* b1 = (const float*)d_in[10];
  const float* W2 = (const float*)d_in[11];
  const float* b2 = (const float*)d_in[12];
  const float* W3 = (const float*)d_in[13];
  const float* b3 = (const float*)d_in[14];

  const int B = in_sizes[0] / (T * D);  // 4096 chains, one wave each
  dim3 grid(B), block(64);
  hipLaunchKernelGGL(rnn_head_fused, grid, block, 0, stream, x, Wih1, Whh1,
                     bih1, bhh1, Wih2, Whh2, bih2, bhh2, W1, b1, W2, b2, W3, b3,
                     (float*)d_out);
}

// Round 3
// 1237.179 us; speedup vs baseline: 1.4581x; 1.0360x over previous
//
#include <hip/hip_runtime.h>

// 2-layer tanh RNN (B=4096, T=512, D=30) + MLP head (30->15->15->1), fp32.
//
// One wave (64 lanes) per batch chain, block=64 -> 4096 blocks (12-16 waves/CU).
// The two 32-lane halves hold DIFFERENT weight arrays so each broadcast-dot
// phase computes two matvecs in one instruction stream:
//   phase1: lower = Whh1 rows (rec1_next), upper = Wih2 rows (layer2 in-proj)
//   phase2: lower = [W1 rows; W2 rows]   , upper = Whh2 rows (rec2_next)
// Hidden-state broadcast via v_readlane -> SGPR, consumed as the scalar
// operand of v_fma. No LDS.
//
// R2 lesson: compiler rematerialized the 90 loop-invariant weight loads into
// the time loop (VGPR_Count=52!). Fix: pin each weight in a VGPR with an
// opaque asm so remat is impossible; launch_bounds(64,3) gives a 170-VGPR
// budget (12 waves/CU, same as measured occupancy).

namespace {
constexpr int T = 512;
constexpr int D = 30;   // hidden size
constexpr int H = 15;   // head hidden size

// tanh(x) = 1 - 2/(exp(2x)+1): NaN-free at +/-inf, ~1e-6 abs err.
__device__ __forceinline__ float fast_tanh(float x) {
  float e = __expf(2.0f * x);
  return 1.0f - 2.0f * __builtin_amdgcn_rcpf(e + 1.0f);
}

// Broadcast lane `lane`'s value to all lanes via v_readlane (SGPR result).
__device__ __forceinline__ float bcast(float v, int lane) {
  return __int_as_float(__builtin_amdgcn_readlane(__float_as_int(v), lane));
}

// Force `v` to live in a VGPR; opaque to the optimizer -> the producing load
// cannot be rematerialized inside the loop.
#define PIN(v) asm volatile("" : "+v"(v))
}  // namespace

__global__ __launch_bounds__(64, 3) void rnn_head_fused(
    const float* __restrict__ x,
    const float* __restrict__ Wih1, const float* __restrict__ Whh1,
    const float* __restrict__ bih1, const float* __restrict__ bhh1,
    const float* __restrict__ Wih2, const float* __restrict__ Whh2,
    const float* __restrict__ bih2, const float* __restrict__ bhh2,
    const float* __restrict__ W1, const float* __restrict__ b1,
    const float* __restrict__ W2, const float* __restrict__ b2,
    const float* __restrict__ W3, const float* __restrict__ b3,
    float* __restrict__ out) {
  const int j = threadIdx.x;           // 0..63
  const bool lo = (j < 32);            // lower half?
  const int ju = lo ? j : (j - 32);    // index within half
  const int r = (ju < D) ? ju : (D - 1);  // clamped row index 0..29

  // ---- per-lane weight rows (registers, pinned) ----
  // dk : Wih1 row r on BOTH halves (in-proj computed redundantly)
  // aw : lower = Whh1 row r, upper = Wih2 row r
  // bw : lower j<15 = W1 row j; lower 15<=j<30 = W2 row (j-15) (cols 0..14);
  //      upper = Whh2 row r
  float dk[D], aw[D], bw[D];
  const float* Drow = Wih1 + r * D;
  const float* Arow = (lo ? Whh1 : Wih2) + r * D;
#pragma unroll
  for (int k = 0; k < D; ++k) {
    dk[k] = Drow[k];
    aw[k] = Arow[k];
  }
#pragma unroll
  for (int k = 0; k < D; ++k) {
    float v;
    if (!lo)
      v = Whh2[r * D + k];
    else if (j < H)
      v = W1[j * D + k];
    else if (j < D && k < H)
      v = W2[(j - H) * H + k];
    else
      v = 0.0f;
    bw[k] = v;
  }
#pragma unroll
  for (int k = 0; k < D; ++k) {
    PIN(dk[k]);
    PIN(aw[k]);
    PIN(bw[k]);
  }

  // biasA: lower = bih1+bhh1 (for h1), upper = bih2+bhh2 (for h2)
  float biasA = lo ? (bih1[r] + bhh1[r]) : (bih2[r] + bhh2[r]);
  // biasB: lanes 0..14 = b1 (for v1), lanes 15..29 = b2 (for v2), else 0
  float biasB = (j < H) ? b1[j] : ((j < D) ? b2[j - H] : 0.0f);
  const bool mid = (j >= H) && (j < D);        // lanes 15..29 hold v2
  float w3v = mid ? W3[j - H] : 0.0f;
  const float sb3 = b3[0];
  PIN(biasA);
  PIN(biasB);
  PIN(w3v);

  const float* xr = x + (long)blockIdx.x * (T * D);
  float* outp = out + (long)blockIdx.x * T;

  // preload x_0
  float sx[D];
#pragma unroll
  for (int k = 0; k < D; ++k) sx[k] = xr[k];

  float rec1 = 0.0f, rec2 = 0.0f;  // Whh1*h1_{t-1} (lower) / Whh2*h2_{t-1} (upper)

  for (int t = 0; t < T; ++t) {
    // ---- layer-1 input projection: Wih1[r,:] . x_t  (+biasA folded in) ----
    float xa = biasA, xb = 0.0f;
#pragma unroll
    for (int k = 0; k < D; ++k) {
      if (k & 1)
        xb = fmaf(dk[k], sx[k], xb);
      else
        xa = fmaf(dk[k], sx[k], xa);
    }
    const float h1 = fast_tanh(xa + xb + rec1);  // valid on lanes 0..29

    // prefetch x_{t+1} (independent; full step of latency slack)
    {
      const float* xn = xr + ((t + 1 < T) ? (t + 1) : t) * D;
#pragma unroll
      for (int k = 0; k < D; ++k) sx[k] = xn[k];
    }

    // ---- phase 1: broadcast h1 (lanes 0..29); lower->rec1_next, upper->p2.
    // rec1 (lower) must stay a pure dot -> no bias folding here.
    float p1a = 0.0f, p1b = 0.0f;
#pragma unroll
    for (int k = 0; k < D; ++k) {
      const float s = bcast(h1, k);
      if (k & 1)
        p1b = fmaf(aw[k], s, p1b);
      else
        p1a = fmaf(aw[k], s, p1a);
    }
    const float p1 = p1a + p1b;
    rec1 = p1;                                           // meaningful on lower
    const float h2 = fast_tanh(p1 + biasA + rec2);       // valid on lanes 32..61

    // ---- phase 2: broadcast h2 (lanes 32..61); lower->u1, upper->rec2_next.
    // biasB folded into p2a: upper lanes have biasB==0 so rec2 stays pure;
    // mid lanes' v1 is unused garbage anyway.
    float p2a = biasB, p2b = 0.0f;
#pragma unroll
    for (int k = 0; k < D; ++k) {
      const float s = bcast(h2, 32 + k);
      if (k & 1)
        p2b = fmaf(bw[k], s, p2b);
      else
        p2a = fmaf(bw[k], s, p2a);
    }
    const float p2 = p2a + p2b;
    rec2 = p2;                                           // meaningful on upper
    const float v1 = fast_tanh(p2);                      // valid on lanes 0..14

    // ---- phase 3: broadcast v1 (lanes 0..14); lanes 15..29 -> u2.
    // biasB folded: mid lanes get b2 (needed); other lanes' v2 unused.
    float p3a = biasB, p3b = 0.0f;
#pragma unroll
    for (int k = 0; k < H; ++k) {
      const float s = bcast(v1, k);
      if (k & 1)
        p3b = fmaf(bw[k], s, p3b);
      else
        p3a = fmaf(bw[k], s, p3a);
    }
    const float v2 = fast_tanh(p3a + p3b);               // valid on lanes 15..29

    // ---- head layer 3: y = sum_i W3[i] * v2[15+i] + b3 ----
    float p = mid ? (w3v * v2) : 0.0f;  // cndmask kills NaN from garbage lanes
    p += __shfl_xor(p, 16, 32);
    p += __shfl_xor(p, 8, 32);
    p += __shfl_xor(p, 4, 32);
    p += __shfl_xor(p, 2, 32);
    p += __shfl_xor(p, 1, 32);
    if (j == 0) outp[t] = p + sb3;
  }
}

extern "C" void kernel_launch(void* const* d_in, const int* in_sizes, int n_in,
                              void* d_out, int out_size, void* d_ws,
                              size_t ws_size, hipStream_t stream) {
  const float* x = (const float*)d_in[0];
  const float* Wih1 = (const float*)d_in[1];
  const float* Whh1 = (const float*)d_in[2];
  const float* bih1 = (const float*)d_in[3];
  const float* bhh1 = (const float*)d_in[4];
  const float* Wih2 = (const float*)d_in[5];
  const float* Whh2 = (const float*)d_in[6];
  const float* bih2 = (const float*)d_in[7];
  const float* bhh2 = (const float*)d_in[8];
  const float* W1 = (const float*)d_in[9];
  const float* b1 = (const float*)d_in[10];
  const float* W2 = (const float*)d_in[11];
  const float* b2 = (const float*)d_in[12];
  const float* W3 = (const float*)d_in[13];
  const float* b3 = (const float*)d_in[14];

  const int B = in_sizes[0] / (T * D);  // 4096 chains, one wave each
  dim3 grid(B), block(64);
  hipLaunchKernelGGL(rnn_head_fused, grid, block, 0, stream, x, Wih1, Whh1,
                     bih1, bhh1, Wih2, Whh2, bih2, bhh2, W1, b1, W2, b2, W3, b3,
                     (float*)d_out);
}